// Round 20
// baseline (311.410 us; speedup 1.0000x reference)
//
#include <hip/hip_runtime.h>
#include <hip/hip_bf16.h>

// StreamingTransformerLayer on MI355X (gfx950).
// T=8192, D=512, DFF=2048. All-f32 in/out; internal GEMMs in bf16 MFMA.
// Round 20: r19 base (309.2us) + wout->LN2 fusion: wout emits raw bf16 GEMM
// out (verified MODE_BF16 path); new resid_ln_kernel (= verified
// resid_combine body + verified ln_kernel body concatenated, wave-per-row)
// computes x1 = x + ls1*wout, writes x1 (residual for the end) AND
// h = LN2(x1) in one pass. Removes one dispatch + 16MB x1 round-trip.

using bf16 = __hip_bfloat16;
typedef __attribute__((ext_vector_type(8))) short short8;   // 8 bf16 = 4 VGPR (MFMA frag)
typedef __attribute__((ext_vector_type(4))) short short4v;  // 4 bf16 = 8B
typedef __attribute__((ext_vector_type(4))) float f32x4;

#define T_DIM 8192

#define AS1C(p) (const __attribute__((address_space(1))) void*)(p)
#define AS3P(p) (__attribute__((address_space(3))) void*)(p)
#define GLL16(src, dst) __builtin_amdgcn_global_load_lds(AS1C(src), AS3P(dst), 16, 0, 0)

static __device__ __forceinline__ short f2bfbits(float f) {
  bf16 b = __float2bfloat16(f);
  short s; __builtin_memcpy(&s, &b, 2); return s;
}
static __device__ __forceinline__ float bfbits2f(short s) {
  unsigned u = ((unsigned)(unsigned short)s) << 16;
  float f; __builtin_memcpy(&f, &u, 4); return f;
}

// ---------------- fused f32 -> bf16 weight convert (vectorized x4) ----------
__global__ void cvt4_kernel(
    const float* __restrict__ a, bf16* __restrict__ oa, int na,
    const float* __restrict__ b, bf16* __restrict__ ob, int nb,
    const float* __restrict__ c, bf16* __restrict__ oc, int nc,
    const float* __restrict__ d, bf16* __restrict__ od, int nd)
{
  int i = blockIdx.x * 256 + threadIdx.x;   // index in groups of 4 floats
  const float* src; bf16* dst;
  if (i < na / 4) { src = a; dst = oa; }
  else { i -= na / 4;
    if (i < nb / 4) { src = b; dst = ob; }
    else { i -= nb / 4;
      if (i < nc / 4) { src = c; dst = oc; }
      else { i -= nc / 4;
        if (i >= nd / 4) return;
        src = d; dst = od; } } }
  const f32x4 v = ((const f32x4*)src)[i];
  short4v o;
#pragma unroll
  for (int j = 0; j < 4; ++j) o[j] = f2bfbits(v[j]);
  ((short4v*)dst)[i] = o;
}

// ---------------- LayerNorm: f32 [T,512] -> bf16 [T,512] (LN1) --------------
__global__ __launch_bounds__(256) void ln_kernel(
    const float* __restrict__ x, const float* __restrict__ g,
    const float* __restrict__ bb, bf16* __restrict__ h)
{
  const int row = blockIdx.x * 4 + (threadIdx.x >> 6);
  const int lane = threadIdx.x & 63;
  const float* xr = x + (size_t)row * 512 + lane * 8;
  f32x4 v0 = *(const f32x4*)xr;
  f32x4 v1 = *(const f32x4*)(xr + 4);
  float s = 0.f;
#pragma unroll
  for (int j = 0; j < 4; ++j) s += v0[j] + v1[j];
#pragma unroll
  for (int d = 1; d < 64; d <<= 1) s += __shfl_xor(s, d);
  const float mu = s * (1.f / 512.f);
  float vs = 0.f;
#pragma unroll
  for (int j = 0; j < 4; ++j) { float a = v0[j] - mu, b2 = v1[j] - mu; vs += a * a + b2 * b2; }
#pragma unroll
  for (int d = 1; d < 64; d <<= 1) vs += __shfl_xor(vs, d);
  const float rs = rsqrtf(vs * (1.f / 512.f) + 1e-5f);
  const f32x4 g0 = *(const f32x4*)(g + lane * 8);
  const f32x4 g1v = *(const f32x4*)(g + lane * 8 + 4);
  const f32x4 b0 = *(const f32x4*)(bb + lane * 8);
  const f32x4 b1v = *(const f32x4*)(bb + lane * 8 + 4);
  short8 ov;
#pragma unroll
  for (int j = 0; j < 4; ++j) {
    ov[j]     = f2bfbits((v0[j] - mu) * rs * g0[j] + b0[j]);
    ov[j + 4] = f2bfbits((v1[j] - mu) * rs * g1v[j] + b1v[j]);
  }
  *(short8*)(h + (size_t)row * 512 + lane * 8) = ov;
}

// ---------------- fused resid + LN: x1 = resid + scale*gout; h = LN(x1) -----
// Concatenation of the verified resid_combine (nc=1) and ln_kernel bodies.
__global__ __launch_bounds__(256) void resid_ln_kernel(
    const bf16* __restrict__ gout, const float* __restrict__ resid,
    const float* __restrict__ scale, const float* __restrict__ g,
    const float* __restrict__ bb, float* __restrict__ x1, bf16* __restrict__ h)
{
  const int row = blockIdx.x * 4 + (threadIdx.x >> 6);
  const int lane = threadIdx.x & 63;
  const short8 u = *(const short8*)(gout + (size_t)row * 512 + lane * 8);
  const float* rp = resid + (size_t)row * 512 + lane * 8;
  const f32x4 r0 = *(const f32x4*)rp;
  const f32x4 r1 = *(const f32x4*)(rp + 4);
  const f32x4 s0 = *(const f32x4*)(scale + lane * 8);
  const f32x4 s1 = *(const f32x4*)(scale + lane * 8 + 4);
  f32x4 v0, v1;
#pragma unroll
  for (int j = 0; j < 4; ++j) {
    v0[j] = r0[j] + s0[j] * bfbits2f(u[j]);
    v1[j] = r1[j] + s1[j] * bfbits2f(u[j + 4]);
  }
  float* op = x1 + (size_t)row * 512 + lane * 8;
  *(f32x4*)op = v0;
  *(f32x4*)(op + 4) = v1;
  // ---- LN (verified ln_kernel math) ----
  float s = 0.f;
#pragma unroll
  for (int j = 0; j < 4; ++j) s += v0[j] + v1[j];
#pragma unroll
  for (int d = 1; d < 64; d <<= 1) s += __shfl_xor(s, d);
  const float mu = s * (1.f / 512.f);
  float vs = 0.f;
#pragma unroll
  for (int j = 0; j < 4; ++j) { float a = v0[j] - mu, b2 = v1[j] - mu; vs += a * a + b2 * b2; }
#pragma unroll
  for (int d = 1; d < 64; d <<= 1) vs += __shfl_xor(vs, d);
  const float rs = rsqrtf(vs * (1.f / 512.f) + 1e-5f);
  const f32x4 g0 = *(const f32x4*)(g + lane * 8);
  const f32x4 g1v = *(const f32x4*)(g + lane * 8 + 4);
  const f32x4 b0 = *(const f32x4*)(bb + lane * 8);
  const f32x4 b1v = *(const f32x4*)(bb + lane * 8 + 4);
  short8 ov;
#pragma unroll
  for (int j = 0; j < 4; ++j) {
    ov[j]     = f2bfbits((v0[j] - mu) * rs * g0[j] + b0[j]);
    ov[j + 4] = f2bfbits((v1[j] - mu) * rs * g1v[j] + b1v[j]);
  }
  *(short8*)(h + (size_t)row * 512 + lane * 8) = ov;
}

enum { MODE_BF16 = 0, MODE_GELU = 1, MODE_RESID = 2 };

static __device__ __forceinline__ float gelu_f(float x) {
  float x3 = x * x * x;
  float t = tanhf(0.7978845608028654f * (x + 0.044715f * x3));
  return 0.5f * x * (1.0f + t);
}

// ---------------- GEMM C = A * B^T (128x128 tile, BK=64, 4 waves) ----------
template <int MODE>
__global__ __launch_bounds__(256, 2) void gemm_bt(
    const bf16* __restrict__ A, const bf16* __restrict__ B,
    int M, int N, int K,
    bf16* __restrict__ Cb, float* __restrict__ Cf,
    const float* __restrict__ resid, const float* __restrict__ scale,
    bf16* __restrict__ vTout)
{
  __shared__ bf16 sA[128 * 64];
  __shared__ bf16 sB[128 * 64];
  const int tid = threadIdx.x;
  const int lane = tid & 63, wave = tid >> 6;
  const int NB = gridDim.y;
  const int nwg = gridDim.x * NB;
  const int lin = blockIdx.y * gridDim.x + blockIdx.x;
  const int q8 = nwg >> 3;
  const int swz = (lin & 7) * q8 + (lin >> 3);
  const int bm = swz / NB, bn = swz % NB;
  const int wm = (wave & 1) * 64, wn = (wave >> 1) * 64;
  const int ln = lane & 15, lg = lane >> 4;
  f32x4 acc[4][4] = {};

  const int nkt = K >> 6;
  for (int kt = 0; kt < nkt; ++kt) {
    __syncthreads();
#pragma unroll
    for (int r = 0; r < 4; ++r) {
      const int s = r * 256 + tid;
      const int ks = s >> 9, rb = (s >> 6) & 7, l = s & 63;
      const bf16* srcA = A + (size_t)(bm * 128 + rb * 16 + (l & 15)) * K + kt * 64 + ks * 32 + (l >> 4) * 8;
      GLL16(srcA, sA + (size_t)(r * 256 + wave * 64) * 8);
      const bf16* srcB = B + (size_t)(bn * 128 + rb * 16 + (l & 15)) * K + kt * 64 + ks * 32 + (l >> 4) * 8;
      GLL16(srcB, sB + (size_t)(r * 256 + wave * 64) * 8);
    }
    __syncthreads();
#pragma unroll
    for (int ks = 0; ks < 2; ++ks) {
      short8 af[4], bfr[4];
#pragma unroll
      for (int mi = 0; mi < 4; ++mi)
        af[mi] = *(const short8*)(sA + (size_t)(ks * 512 + ((wm >> 4) + mi) * 64 + lane) * 8);
#pragma unroll
      for (int ni = 0; ni < 4; ++ni)
        bfr[ni] = *(const short8*)(sB + (size_t)(ks * 512 + ((wn >> 4) + ni) * 64 + lane) * 8);
#pragma unroll
      for (int mi = 0; mi < 4; ++mi)
#pragma unroll
        for (int ni = 0; ni < 4; ++ni)
          acc[mi][ni] = __builtin_amdgcn_mfma_f32_16x16x32_bf16(af[mi], bfr[ni], acc[mi][ni], 0, 0, 0);
    }
  }
#pragma unroll
  for (int mi = 0; mi < 4; ++mi) {
#pragma unroll
    for (int ni = 0; ni < 4; ++ni) {
#pragma unroll
      for (int r = 0; r < 4; ++r) {
        const int row = bm * 128 + wm + mi * 16 + lg * 4 + r;
        const int col = bn * 128 + wn + ni * 16 + ln;
        const size_t idx = (size_t)row * N + col;
        float v = acc[mi][ni][r];
        if constexpr (MODE == MODE_GELU) { Cb[idx] = __float2bfloat16(gelu_f(v)); }
        else if constexpr (MODE == MODE_RESID) { Cf[idx] = resid[idx] + scale[col] * v; }
        else {
          const bf16 bv = __float2bfloat16(v);
          Cb[idx] = bv;
          if (vTout && bn >= 8)
            vTout[(size_t)(col - 1024) * T_DIM + row] = bv;
        }
      }
    }
  }
}

// ---------------- split-K GEMM: partials[z] = A[:, zKc:(z+1)Kc] * B^T ------
__global__ __launch_bounds__(256, 2) void gemm_bt_splitk(
    const bf16* __restrict__ A, const bf16* __restrict__ B,
    int M, int N, int Kc, int ld, bf16* __restrict__ Cb)
{
  __shared__ bf16 sA[128 * 64];
  __shared__ bf16 sB[128 * 64];
  const int tid = threadIdx.x;
  const int lane = tid & 63, wave = tid >> 6;
  const int NB = gridDim.y;
  const int nwg = gridDim.x * NB;
  const int lin = blockIdx.y * gridDim.x + blockIdx.x;
  const int q8 = nwg >> 3;
  const int swz = (lin & 7) * q8 + (lin >> 3);
  const int bm = swz / NB, bn = swz % NB;
  const int z = blockIdx.z;
  const int koff = z * Kc;
  const int wm = (wave & 1) * 64, wn = (wave >> 1) * 64;
  const int ln = lane & 15, lg = lane >> 4;
  f32x4 acc[4][4] = {};

  const int nkt = Kc >> 6;
  for (int kt = 0; kt < nkt; ++kt) {
    __syncthreads();
#pragma unroll
    for (int r = 0; r < 4; ++r) {
      const int s = r * 256 + tid;
      const int ks = s >> 9, rb = (s >> 6) & 7, l = s & 63;
      const bf16* srcA = A + (size_t)(bm * 128 + rb * 16 + (l & 15)) * ld + koff + kt * 64 + ks * 32 + (l >> 4) * 8;
      GLL16(srcA, sA + (size_t)(r * 256 + wave * 64) * 8);
      const bf16* srcB = B + (size_t)(bn * 128 + rb * 16 + (l & 15)) * ld + koff + kt * 64 + ks * 32 + (l >> 4) * 8;
      GLL16(srcB, sB + (size_t)(r * 256 + wave * 64) * 8);
    }
    __syncthreads();
#pragma unroll
    for (int ks = 0; ks < 2; ++ks) {
      short8 af[4], bfr[4];
#pragma unroll
      for (int mi = 0; mi < 4; ++mi)
        af[mi] = *(const short8*)(sA + (size_t)(ks * 512 + ((wm >> 4) + mi) * 64 + lane) * 8);
#pragma unroll
      for (int ni = 0; ni < 4; ++ni)
        bfr[ni] = *(const short8*)(sB + (size_t)(ks * 512 + ((wn >> 4) + ni) * 64 + lane) * 8);
#pragma unroll
      for (int mi = 0; mi < 4; ++mi)
#pragma unroll
        for (int ni = 0; ni < 4; ++ni)
          acc[mi][ni] = __builtin_amdgcn_mfma_f32_16x16x32_bf16(af[mi], bfr[ni], acc[mi][ni], 0, 0, 0);
    }
  }
#pragma unroll
  for (int mi = 0; mi < 4; ++mi)
#pragma unroll
    for (int ni = 0; ni < 4; ++ni)
#pragma unroll
      for (int r = 0; r < 4; ++r) {
        const int row = bm * 128 + wm + mi * 16 + lg * 4 + r;
        const int col = bn * 128 + wn + ni * 16 + ln;
        Cb[((size_t)z * M + row) * N + col] = __float2bfloat16(acc[mi][ni][r]);
      }
}

// ---------------- resid combine: out = resid + scale * sum(chunks) ---------
__global__ __launch_bounds__(256) void resid_combine(
    const bf16* __restrict__ Opc, int nc,
    const float* __restrict__ resid, const float* __restrict__ scale,
    float* __restrict__ outp)
{
  const int row = blockIdx.x * 4 + (threadIdx.x >> 6);
  const int lane = threadIdx.x & 63;
  f32x4 a0 = {}, a1 = {};
  for (int c = 0; c < nc; ++c) {
    const short8 u = *(const short8*)(Opc + ((size_t)c * T_DIM + row) * 512 + lane * 8);
#pragma unroll
    for (int j = 0; j < 4; ++j) {
      a0[j] += bfbits2f(u[j]);
      a1[j] += bfbits2f(u[j + 4]);
    }
  }
  const float* rp = resid + (size_t)row * 512 + lane * 8;
  const f32x4 r0 = *(const f32x4*)rp;
  const f32x4 r1 = *(const f32x4*)(rp + 4);
  const f32x4 s0 = *(const f32x4*)(scale + lane * 8);
  const f32x4 s1 = *(const f32x4*)(scale + lane * 8 + 4);
  f32x4 o0, o1;
#pragma unroll
  for (int j = 0; j < 4; ++j) {
    o0[j] = r0[j] + s0[j] * a0[j];
    o1[j] = r1[j] + s1[j] * a1[j];
  }
  float* op = outp + (size_t)row * 512 + lane * 8;
  *(f32x4*)op = o0;
  *(f32x4*)(op + 4) = o1;
}

// ---------------- GEMM C = A * B^T (256x128 tile, BK=64, 8 waves) ----------
template <int MODE>
__global__ __launch_bounds__(512, 4) void gemm_bt256(
    const bf16* __restrict__ A, const bf16* __restrict__ B,
    int M, int N, int K,
    bf16* __restrict__ Cb, bf16* __restrict__ vTout)
{
  __shared__ bf16 sA[256 * 64];
  __shared__ bf16 sB[128 * 64];
  const int tid = threadIdx.x;
  const int lane = tid & 63, wave = tid >> 6;
  const int NB = gridDim.y;
  const int nwg = gridDim.x * NB;
  const int lin = blockIdx.y * gridDim.x + blockIdx.x;
  const int q8 = nwg >> 3;
  const int swz = (lin & 7) * q8 + (lin >> 3);
  const int bm = swz / NB, bn = swz % NB;
  const int wm = (wave & 3) * 64, wn = (wave >> 2) * 64;
  const int ln = lane & 15, lg = lane >> 4;
  f32x4 acc[4][4] = {};

  const int nkt = K >> 6;
  for (int kt = 0; kt < nkt; ++kt) {
    __syncthreads();
#pragma unroll
    for (int r = 0; r < 4; ++r) {
      const int s = r * 512 + tid;
      const int ks = s >> 10, rb = (s >> 6) & 15, l = s & 63;
      const bf16* srcA = A + (size_t)(bm * 256 + rb * 16 + (l & 15)) * K + kt * 64 + ks * 32 + (l >> 4) * 8;
      GLL16(srcA, sA + (size_t)(r * 512 + wave * 64) * 8);
    }
#pragma unroll
    for (int r = 0; r < 2; ++r) {
      const int s = r * 512 + tid;
      const int ks = s >> 9, rb = (s >> 6) & 7, l = s & 63;
      const bf16* srcB = B + (size_t)(bn * 128 + rb * 16 + (l & 15)) * K + kt * 64 + ks * 32 + (l >> 4) * 8;
      GLL16(srcB, sB + (size_t)(r * 512 + wave * 64) * 8);
    }
    __syncthreads();
#pragma unroll
    for (int ks = 0; ks < 2; ++ks) {
      short8 af[4], bfr[4];
#pragma unroll
      for (int mi = 0; mi < 4; ++mi)
        af[mi] = *(const short8*)(sA + (size_t)(ks * 1024 + ((wm >> 4) + mi) * 64 + lane) * 8);
#pragma unroll
      for (int ni = 0; ni < 4; ++ni)
        bfr[ni] = *(const short8*)(sB + (size_t)(ks * 512 + ((wn >> 4) + ni) * 64 + lane) * 8);
#pragma unroll
      for (int mi = 0; mi < 4; ++mi)
#pragma unroll
        for (int ni = 0; ni < 4; ++ni)
          acc[mi][ni] = __builtin_amdgcn_mfma_f32_16x16x32_bf16(af[mi], bfr[ni], acc[mi][ni], 0, 0, 0);
    }
  }
#pragma unroll
  for (int mi = 0; mi < 4; ++mi) {
#pragma unroll
    for (int ni = 0; ni < 4; ++ni) {
#pragma unroll
      for (int r = 0; r < 4; ++r) {
        const int row = bm * 256 + wm + mi * 16 + lg * 4 + r;
        const int col = bn * 128 + wn + ni * 16 + ln;
        const size_t idx = (size_t)row * N + col;
        float v = acc[mi][ni][r];
        if constexpr (MODE == MODE_GELU) { Cb[idx] = __float2bfloat16(gelu_f(v)); }
        else {
          const bf16 bv = __float2bfloat16(v);
          Cb[idx] = bv;
          if (vTout && bn >= 8)
            vTout[(size_t)(col - 1024) * T_DIM + row] = bv;
        }
      }
    }
  }
}

// ---------------- causal flash attention (8 waves, 128 rows, T4 + T13) ------
// (unchanged -- verified at 147us)
__global__ __launch_bounds__(512, 2) void attn_kernel(
    const bf16* __restrict__ proj, const bf16* __restrict__ vT,
    bf16* __restrict__ Op, float* __restrict__ mlp)
{
  __shared__ bf16 sQ[2][32 * 512];
  __shared__ bf16 sV[2][32 * 512];
  __shared__ bf16 sP[8][16 * 40];

  const int tid = threadIdx.x, lane = tid & 63, wave = tid >> 6;
  const int ln = lane & 15, lg = lane >> 4;
  const int b = 511 - blockIdx.x;
  const int it = b >> 3;
  const int ch = b & 7;
  const int nj = 4 * it + 4;
  const int jlo = ch * nj / 8;
  const int jhi = (ch + 1) * nj / 8;
  const int wrow = it * 128 + wave * 16;

  short8 kf[16];
#pragma unroll
  for (int ks = 0; ks < 16; ++ks)
    kf[ks] = *(const short8*)(proj + (size_t)(wrow + ln) * 1536 + 512 + ks * 32 + lg * 8);

  f32x4 oa[32] = {};
  float m_r[4] = {-__builtin_inff(), -__builtin_inff(), -__builtin_inff(), -__builtin_inff()};
  float l_r[4] = {0.f, 0.f, 0.f, 0.f};

  auto stageQ = [&](int c, int jt) {
    const int j0 = jt * 32;
#pragma unroll
    for (int r = 0; r < 4; ++r) {
      const int s = r * 512 + tid;
      const int l = s & 63;
      const int ks = s >> 7, jb = (s >> 6) & 1;
      const bf16* srcQ = proj + (size_t)(j0 + jb * 16 + (l & 15)) * 1536 + ks * 32 + (l >> 4) * 8;
      GLL16(srcQ, &sQ[c][(size_t)(r * 512 + wave * 64) * 8]);
    }
  };
  auto stageV = [&](int c, int jt) {
    const int j0 = jt * 32;
#pragma unroll
    for (int r = 0; r < 4; ++r) {
      const int s = r * 512 + tid;
      const int l = s & 63;
      const int nb = s >> 6;
      const bf16* srcV = vT + (size_t)(nb * 16 + (l & 15)) * T_DIM + j0 + (l >> 4) * 8;
      GLL16(srcV, &sV[c][(size_t)(r * 512 + wave * 64) * 8]);
    }
  };

  if (jlo < jhi) {
    int cur = 0;
    stageQ(0, jlo);
    stageV(0, jlo);
    for (int jt = jlo; jt < jhi; ++jt) {
      const int j0 = jt * 32;
      const bool more = (jt + 1 < jhi);
      if (more) stageQ(cur ^ 1, jt + 1);
      if (more) { asm volatile("s_waitcnt vmcnt(8)" ::: "memory"); }
      else      { asm volatile("s_waitcnt vmcnt(4)" ::: "memory"); }
      __builtin_amdgcn_s_barrier();
      __builtin_amdgcn_sched_barrier(0);
      if (j0 <= wrow + 15) {
        f32x4 sfr[2] = {};
        __builtin_amdgcn_s_setprio(1);
#pragma unroll
        for (int ks = 0; ks < 16; ++ks) {
          short8 q0 = *(const short8*)(&sQ[cur][(size_t)(ks * 128 + lane) * 8]);
          short8 q1 = *(const short8*)(&sQ[cur][(size_t)(ks * 128 + 64 + lane) * 8]);
          sfr[0] = __builtin_amdgcn_mfma_f32_16x16x32_bf16(kf[ks], q0, sfr[0], 0, 0, 0);
          sfr[1] = __builtin_amdgcn_mfma_f32_16x16x32_bf16(kf[ks], q1, sfr[1], 0, 0, 0);
        }
        __builtin_amdgcn_s_setprio(0);
        if (j0 + 31 > wrow) {
#pragma unroll
          for (int jb = 0; jb < 2; ++jb)
#pragma unroll
            for (int r = 0; r < 4; ++r) {
              const int i = wrow + lg * 4 + r, j = j0 + jb * 16 + ln;
              if (j > i) sfr[jb][r] = -__builtin_inff();
            }
        }
        float mx[4];
#pragma unroll
        for (int r = 0; r < 4; ++r) mx[r] = fmaxf(sfr[0][r], sfr[1][r]);
#pragma unroll
        for (int d = 1; d < 16; d <<= 1)
#pragma unroll
          for (int r = 0; r < 4; ++r) mx[r] = fmaxf(mx[r], __shfl_xor(mx[r], d));
        bool need = false;
#pragma unroll
        for (int r = 0; r < 4; ++r) need |= !(mx[r] - m_r[r] <= 8.0f);
        if (__any(need)) {
          float sc[4];
#pragma unroll
          for (int r = 0; r < 4; ++r) {
            float mm = fmaxf(fmaxf(m_r[r], mx[r]), -1e30f);
            sc[r] = __expf(m_r[r] - mm);
            m_r[r] = mm;
            l_r[r] *= sc[r];
          }
#pragma unroll
          for (int nb = 0; nb < 32; ++nb)
#pragma unroll
            for (int r = 0; r < 4; ++r) oa[nb][r] *= sc[r];
        }
        float ts[4] = {0.f, 0.f, 0.f, 0.f};
#pragma unroll
        for (int jb = 0; jb < 2; ++jb)
#pragma unroll
          for (int r = 0; r < 4; ++r) {
            float p = __expf(sfr[jb][r] - m_r[r]);
            sfr[jb][r] = p;
            ts[r] += p;
          }
#pragma unroll
        for (int d = 1; d < 16; d <<= 1)
#pragma unroll
          for (int r = 0; r < 4; ++r) ts[r] += __shfl_xor(ts[r], d);
#pragma unroll
        for (int r = 0; r < 4; ++r) l_r[r] += ts[r];
#pragma unroll
        for (int jb = 0; jb < 2; ++jb)
#pragma unroll
          for (int r = 0; r < 4; ++r)
            sP[wave][(lg * 4 + r) * 40 + jb * 16 + ln] = __float2bfloat16(sfr[jb][r]);
      }
      if (more) stageV(cur ^ 1, jt + 1);
      if (more) { asm volatile("s_waitcnt vmcnt(8)" ::: "memory"); }
      else      { asm volatile("s_waitcnt vmcnt(0)" ::: "memory"); }
      __builtin_amdgcn_s_barrier();
      __builtin_amdgcn_sched_barrier(0);
      if (j0 <= wrow + 15) {
        const short8 pa = *(const short8*)(&sP[wave][0] + ln * 40 + lg * 8);
        __builtin_amdgcn_s_setprio(1);
#define LDV(nb) (*(const short8*)(&sV[cur][(size_t)((nb) * 64 + lane) * 8]))
        short8 vf0 = LDV(0), vf1 = LDV(1), vf2 = LDV(2), vf3 = LDV(3);
#pragma unroll
        for (int nb = 0; nb < 28; nb += 4) {
          const short8 w0 = vf0, w1 = vf1, w2 = vf2, w3 = vf3;
          vf0 = LDV(nb + 4); vf1 = LDV(nb + 5); vf2 = LDV(nb + 6); vf3 = LDV(nb + 7);
          oa[nb]     = __builtin_amdgcn_mfma_f32_16x16x32_bf16(pa, w0, oa[nb],     0, 0, 0);
          oa[nb + 1] = __builtin_amdgcn_mfma_f32_16x16x32_bf16(pa, w1, oa[nb + 1], 0, 0, 0);
          oa[nb + 2] = __builtin_amdgcn_mfma_f32_16x16x32_bf16(pa, w2, oa[nb + 2], 0, 0, 0);
          oa[nb + 3] = __builtin_amdgcn_mfma_f32_16x16x32_bf16(pa, w3, oa[nb + 3], 0, 0, 0);
        }
        oa[28] = __builtin_amdgcn_mfma_f32_16x16x32_bf16(pa, vf0, oa[28], 0, 0, 0);
        oa[29] = __builtin_amdgcn_mfma_f32_16x16x32_bf16(pa, vf1, oa[29], 0, 0, 0);
        oa[30] = __builtin_amdgcn_mfma_f32_16x16x32_bf16(pa, vf2, oa[30], 0, 0, 0);
        oa[31] = __builtin_amdgcn_mfma_f32_16x16x32_bf16(pa, vf3, oa[31], 0, 0, 0);
#undef LDV
        __builtin_amdgcn_s_setprio(0);
      }
      cur ^= 1;
    }
  }
#pragma unroll
  for (int nb = 0; nb < 32; ++nb)
#pragma unroll
    for (int r = 0; r < 4; ++r)
      Op[((size_t)ch * T_DIM + wrow + lg * 4 + r) * 512 + nb * 16 + ln] = __float2bfloat16(oa[nb][r]);
  if (ln == 0) {
#pragma unroll
    for (int r = 0; r < 4; ++r) {
      mlp[((size_t)ch * T_DIM + wrow + lg * 4 + r) * 2 + 0] = m_r[r];
      mlp[((size_t)ch * T_DIM + wrow + lg * 4 + r) * 2 + 1] = l_r[r];
    }
  }
}

// ---------------- merge attention partials -> o bf16 [T,512] ----------------
__global__ __launch_bounds__(256) void combine_kernel(
    const bf16* __restrict__ Op, const float* __restrict__ mlp, bf16* __restrict__ o)
{
  const int row = blockIdx.x * 4 + (threadIdx.x >> 6);
  const int lane = threadIdx.x & 63;
  const int k = 8;
  float m = -__builtin_inff();
  for (int c = 0; c < k; ++c) m = fmaxf(m, mlp[((size_t)c * T_DIM + row) * 2]);
  float l = 0.f;
  for (int c = 0; c < k; ++c) {
    const float mc = mlp[((size_t)c * T_DIM + row) * 2];
    const float lc = mlp[((size_t)c * T_DIM + row) * 2 + 1];
    l += __expf(mc - m) * lc;
  }
  const float inv = 1.0f / l;
  f32x4 a0 = {}, a1 = {};
  for (int c = 0; c < k; ++c) {
    const float w = __expf(mlp[((size_t)c * T_DIM + row) * 2] - m);
    const short8 u = *(const short8*)(Op + ((size_t)c * T_DIM + row) * 512 + lane * 8);
#pragma unroll
    for (int j = 0; j < 4; ++j) {
      a0[j] += w * bfbits2f(u[j]);
      a1[j] += w * bfbits2f(u[j + 4]);
    }
  }
  short8 ov;
#pragma unroll
  for (int j = 0; j < 4; ++j) {
    ov[j]     = f2bfbits(a0[j] * inv);
    ov[j + 4] = f2bfbits(a1[j] * inv);
  }
  *(short8*)(o + (size_t)row * 512 + lane * 8) = ov;
}

// ---------------- launch ----------------
extern "C" void kernel_launch(void* const* d_in, const int* in_sizes, int n_in,
                              void* d_out, int out_size, void* d_ws, size_t ws_size,
                              hipStream_t stream) {
  (void)in_sizes; (void)n_in; (void)out_size; (void)ws_size;
  const float* x    = (const float*)d_in[0];
  const float* Win  = (const float*)d_in[1];
  const float* Wout = (const float*)d_in[2];
  const float* W1   = (const float*)d_in[3];
  const float* W2   = (const float*)d_in[4];
  const float* g1   = (const float*)d_in[5];
  const float* b1   = (const float*)d_in[6];
  const float* g2   = (const float*)d_in[7];
  const float* b2   = (const float*)d_in[8];
  const float* ls1  = (const float*)d_in[9];
  const float* ls2  = (const float*)d_in[10];
  float* out = (float*)d_out;

  char* w = (char*)d_ws;
  size_t off = 0;
  auto alloc = [&](size_t bytes) -> char* {
    char* p = w + off; off += (bytes + 255) & ~(size_t)255; return p;
  };
  bf16* wWin  = (bf16*)alloc((size_t)1536 * 512 * 2);
  bf16* wWout = (bf16*)alloc((size_t)512 * 512 * 2);
  bf16* wW1   = (bf16*)alloc((size_t)2048 * 512 * 2);
  bf16* wW2   = (bf16*)alloc((size_t)512 * 2048 * 2);
  bf16* h     = (bf16*)alloc((size_t)T_DIM * 512 * 2);    // LN1 out; reused for LN2 out
  bf16* proj  = (bf16*)alloc((size_t)T_DIM * 1536 * 2);   // q|k|v
  bf16* vTb   = (bf16*)alloc((size_t)512 * T_DIM * 2);
  bf16* o     = (bf16*)alloc((size_t)T_DIM * 512 * 2);
  float* x1   = (float*)alloc((size_t)T_DIM * 512 * 4);
  bf16* Op    = (bf16*)alloc((size_t)8 * T_DIM * 512 * 2); // 67MB bf16 partials
  float* mlp  = (float*)alloc((size_t)8 * T_DIM * 2 * 4);
  bf16* f1  = proj;                              // ffn1 out aliases proj||vT (dead after attention)
  bf16* Opf = Op;                                // ffn2 split-K partials (slices 0-1) alias Op
  bf16* ow  = Op + (size_t)4 * T_DIM * 512;      // raw wout GEMM out (slice 4, dead region)

  cvt4_kernel<<<(1536 * 512 + 512 * 512 + 2048 * 512 + 512 * 2048) / 4 / 256, 256, 0, stream>>>(
      Win, wWin, 1536 * 512, Wout, wWout, 512 * 512,
      W1, wW1, 2048 * 512, W2, wW2, 512 * 2048);

  ln_kernel<<<T_DIM / 4, 256, 0, stream>>>(x, g1, b1, h);
  gemm_bt256<MODE_BF16><<<dim3(32, 12), 512, 0, stream>>>(h, wWin, 8192, 1536, 512, proj, vTb);
  attn_kernel<<<512, 512, 0, stream>>>(proj, vTb, Op, mlp);
  combine_kernel<<<T_DIM / 4, 256, 0, stream>>>(Op, mlp, o);
  // wout: raw bf16 GEMM out, then fused (x + ls1*ow) -> x1 AND LN2 -> h.
  gemm_bt<MODE_BF16><<<dim3(64, 4), 256, 0, stream>>>(o, wWout, 8192, 512, 512, ow, nullptr, nullptr, nullptr, nullptr);
  resid_ln_kernel<<<T_DIM / 4, 256, 0, stream>>>(ow, x, ls1, g2, b2, x1, h);
  gemm_bt256<MODE_GELU><<<dim3(32, 16), 512, 0, stream>>>(h, wW1, 8192, 2048, 512, f1, nullptr);
  // ffn2: split-K x2 (Kc=1024, ld=2048) -> 512 blocks, then out = x1 + ls2*(c0+c1).
  gemm_bt_splitk<<<dim3(64, 4, 2), 256, 0, stream>>>(f1, wW2, 8192, 512, 1024, 2048, Opf);
  resid_combine<<<T_DIM / 4, 256, 0, stream>>>(Opf, 2, x1, ls2, out);
}

// Round 21
// 308.928 us; speedup vs baseline: 1.0080x; 1.0080x over previous
//
#include <hip/hip_runtime.h>
#include <hip/hip_bf16.h>

// StreamingTransformerLayer on MI355X (gfx950).
// T=8192, D=512, DFF=2048. All-f32 in/out; internal GEMMs in bf16 MFMA.
// Round 21: revert to the verified round-19 configuration (309.2us, session
// best): 256-tile qkv/ffn1, XCD-swizzled single-buffer GEMMs, MODE_RESID
// inline residual for wout, split-K x2 ffn2 + resid_combine, T4+T13
// attention (147us, structural plateau).

using bf16 = __hip_bfloat16;
typedef __attribute__((ext_vector_type(8))) short short8;   // 8 bf16 = 4 VGPR (MFMA frag)
typedef __attribute__((ext_vector_type(4))) short short4v;  // 4 bf16 = 8B
typedef __attribute__((ext_vector_type(4))) float f32x4;

#define T_DIM 8192

#define AS1C(p) (const __attribute__((address_space(1))) void*)(p)
#define AS3P(p) (__attribute__((address_space(3))) void*)(p)
#define GLL16(src, dst) __builtin_amdgcn_global_load_lds(AS1C(src), AS3P(dst), 16, 0, 0)

static __device__ __forceinline__ short f2bfbits(float f) {
  bf16 b = __float2bfloat16(f);
  short s; __builtin_memcpy(&s, &b, 2); return s;
}
static __device__ __forceinline__ float bfbits2f(short s) {
  unsigned u = ((unsigned)(unsigned short)s) << 16;
  float f; __builtin_memcpy(&f, &u, 4); return f;
}

// ---------------- fused f32 -> bf16 weight convert (vectorized x4) ----------
__global__ void cvt4_kernel(
    const float* __restrict__ a, bf16* __restrict__ oa, int na,
    const float* __restrict__ b, bf16* __restrict__ ob, int nb,
    const float* __restrict__ c, bf16* __restrict__ oc, int nc,
    const float* __restrict__ d, bf16* __restrict__ od, int nd)
{
  int i = blockIdx.x * 256 + threadIdx.x;   // index in groups of 4 floats
  const float* src; bf16* dst;
  if (i < na / 4) { src = a; dst = oa; }
  else { i -= na / 4;
    if (i < nb / 4) { src = b; dst = ob; }
    else { i -= nb / 4;
      if (i < nc / 4) { src = c; dst = oc; }
      else { i -= nc / 4;
        if (i >= nd / 4) return;
        src = d; dst = od; } } }
  const f32x4 v = ((const f32x4*)src)[i];
  short4v o;
#pragma unroll
  for (int j = 0; j < 4; ++j) o[j] = f2bfbits(v[j]);
  ((short4v*)dst)[i] = o;
}

// ---------------- LayerNorm: f32 [T,512] -> bf16 [T,512] ----------------
__global__ __launch_bounds__(256) void ln_kernel(
    const float* __restrict__ x, const float* __restrict__ g,
    const float* __restrict__ bb, bf16* __restrict__ h)
{
  const int row = blockIdx.x * 4 + (threadIdx.x >> 6);
  const int lane = threadIdx.x & 63;
  const float* xr = x + (size_t)row * 512 + lane * 8;
  f32x4 v0 = *(const f32x4*)xr;
  f32x4 v1 = *(const f32x4*)(xr + 4);
  float s = 0.f;
#pragma unroll
  for (int j = 0; j < 4; ++j) s += v0[j] + v1[j];
#pragma unroll
  for (int d = 1; d < 64; d <<= 1) s += __shfl_xor(s, d);
  const float mu = s * (1.f / 512.f);
  float vs = 0.f;
#pragma unroll
  for (int j = 0; j < 4; ++j) { float a = v0[j] - mu, b2 = v1[j] - mu; vs += a * a + b2 * b2; }
#pragma unroll
  for (int d = 1; d < 64; d <<= 1) vs += __shfl_xor(vs, d);
  const float rs = rsqrtf(vs * (1.f / 512.f) + 1e-5f);
  const f32x4 g0 = *(const f32x4*)(g + lane * 8);
  const f32x4 g1v = *(const f32x4*)(g + lane * 8 + 4);
  const f32x4 b0 = *(const f32x4*)(bb + lane * 8);
  const f32x4 b1v = *(const f32x4*)(bb + lane * 8 + 4);
  short8 ov;
#pragma unroll
  for (int j = 0; j < 4; ++j) {
    ov[j]     = f2bfbits((v0[j] - mu) * rs * g0[j] + b0[j]);
    ov[j + 4] = f2bfbits((v1[j] - mu) * rs * g1v[j] + b1v[j]);
  }
  *(short8*)(h + (size_t)row * 512 + lane * 8) = ov;
}

enum { MODE_BF16 = 0, MODE_GELU = 1, MODE_RESID = 2 };

static __device__ __forceinline__ float gelu_f(float x) {
  float x3 = x * x * x;
  float t = tanhf(0.7978845608028654f * (x + 0.044715f * x3));
  return 0.5f * x * (1.0f + t);
}

// ---------------- GEMM C = A * B^T (128x128 tile, BK=64, 4 waves) ----------
// r12 schedule (single-buffer, __syncthreads, XCD swizzle). Used for wout.
template <int MODE>
__global__ __launch_bounds__(256, 2) void gemm_bt(
    const bf16* __restrict__ A, const bf16* __restrict__ B,
    int M, int N, int K,
    bf16* __restrict__ Cb, float* __restrict__ Cf,
    const float* __restrict__ resid, const float* __restrict__ scale,
    bf16* __restrict__ vTout)
{
  __shared__ bf16 sA[128 * 64];
  __shared__ bf16 sB[128 * 64];
  const int tid = threadIdx.x;
  const int lane = tid & 63, wave = tid >> 6;
  const int NB = gridDim.y;
  const int nwg = gridDim.x * NB;
  const int lin = blockIdx.y * gridDim.x + blockIdx.x;
  const int q8 = nwg >> 3;
  const int swz = (lin & 7) * q8 + (lin >> 3);
  const int bm = swz / NB, bn = swz % NB;
  const int wm = (wave & 1) * 64, wn = (wave >> 1) * 64;
  const int ln = lane & 15, lg = lane >> 4;
  f32x4 acc[4][4] = {};

  const int nkt = K >> 6;
  for (int kt = 0; kt < nkt; ++kt) {
    __syncthreads();
#pragma unroll
    for (int r = 0; r < 4; ++r) {
      const int s = r * 256 + tid;
      const int ks = s >> 9, rb = (s >> 6) & 7, l = s & 63;
      const bf16* srcA = A + (size_t)(bm * 128 + rb * 16 + (l & 15)) * K + kt * 64 + ks * 32 + (l >> 4) * 8;
      GLL16(srcA, sA + (size_t)(r * 256 + wave * 64) * 8);
      const bf16* srcB = B + (size_t)(bn * 128 + rb * 16 + (l & 15)) * K + kt * 64 + ks * 32 + (l >> 4) * 8;
      GLL16(srcB, sB + (size_t)(r * 256 + wave * 64) * 8);
    }
    __syncthreads();
#pragma unroll
    for (int ks = 0; ks < 2; ++ks) {
      short8 af[4], bfr[4];
#pragma unroll
      for (int mi = 0; mi < 4; ++mi)
        af[mi] = *(const short8*)(sA + (size_t)(ks * 512 + ((wm >> 4) + mi) * 64 + lane) * 8);
#pragma unroll
      for (int ni = 0; ni < 4; ++ni)
        bfr[ni] = *(const short8*)(sB + (size_t)(ks * 512 + ((wn >> 4) + ni) * 64 + lane) * 8);
#pragma unroll
      for (int mi = 0; mi < 4; ++mi)
#pragma unroll
        for (int ni = 0; ni < 4; ++ni)
          acc[mi][ni] = __builtin_amdgcn_mfma_f32_16x16x32_bf16(af[mi], bfr[ni], acc[mi][ni], 0, 0, 0);
    }
  }
#pragma unroll
  for (int mi = 0; mi < 4; ++mi) {
#pragma unroll
    for (int ni = 0; ni < 4; ++ni) {
#pragma unroll
      for (int r = 0; r < 4; ++r) {
        const int row = bm * 128 + wm + mi * 16 + lg * 4 + r;
        const int col = bn * 128 + wn + ni * 16 + ln;
        const size_t idx = (size_t)row * N + col;
        float v = acc[mi][ni][r];
        if constexpr (MODE == MODE_GELU) { Cb[idx] = __float2bfloat16(gelu_f(v)); }
        else if constexpr (MODE == MODE_RESID) { Cf[idx] = resid[idx] + scale[col] * v; }
        else {
          const bf16 bv = __float2bfloat16(v);
          Cb[idx] = bv;
          if (vTout && bn >= 8)
            vTout[(size_t)(col - 1024) * T_DIM + row] = bv;
        }
      }
    }
  }
}

// ---------------- split-K GEMM: partials[z] = A[:, zKc:(z+1)Kc] * B^T ------
__global__ __launch_bounds__(256, 2) void gemm_bt_splitk(
    const bf16* __restrict__ A, const bf16* __restrict__ B,
    int M, int N, int Kc, int ld, bf16* __restrict__ Cb)
{
  __shared__ bf16 sA[128 * 64];
  __shared__ bf16 sB[128 * 64];
  const int tid = threadIdx.x;
  const int lane = tid & 63, wave = tid >> 6;
  const int NB = gridDim.y;
  const int nwg = gridDim.x * NB;
  const int lin = blockIdx.y * gridDim.x + blockIdx.x;
  const int q8 = nwg >> 3;
  const int swz = (lin & 7) * q8 + (lin >> 3);
  const int bm = swz / NB, bn = swz % NB;
  const int z = blockIdx.z;
  const int koff = z * Kc;
  const int wm = (wave & 1) * 64, wn = (wave >> 1) * 64;
  const int ln = lane & 15, lg = lane >> 4;
  f32x4 acc[4][4] = {};

  const int nkt = Kc >> 6;
  for (int kt = 0; kt < nkt; ++kt) {
    __syncthreads();
#pragma unroll
    for (int r = 0; r < 4; ++r) {
      const int s = r * 256 + tid;
      const int ks = s >> 9, rb = (s >> 6) & 7, l = s & 63;
      const bf16* srcA = A + (size_t)(bm * 128 + rb * 16 + (l & 15)) * ld + koff + kt * 64 + ks * 32 + (l >> 4) * 8;
      GLL16(srcA, sA + (size_t)(r * 256 + wave * 64) * 8);
      const bf16* srcB = B + (size_t)(bn * 128 + rb * 16 + (l & 15)) * ld + koff + kt * 64 + ks * 32 + (l >> 4) * 8;
      GLL16(srcB, sB + (size_t)(r * 256 + wave * 64) * 8);
    }
    __syncthreads();
#pragma unroll
    for (int ks = 0; ks < 2; ++ks) {
      short8 af[4], bfr[4];
#pragma unroll
      for (int mi = 0; mi < 4; ++mi)
        af[mi] = *(const short8*)(sA + (size_t)(ks * 512 + ((wm >> 4) + mi) * 64 + lane) * 8);
#pragma unroll
      for (int ni = 0; ni < 4; ++ni)
        bfr[ni] = *(const short8*)(sB + (size_t)(ks * 512 + ((wn >> 4) + ni) * 64 + lane) * 8);
#pragma unroll
      for (int mi = 0; mi < 4; ++mi)
#pragma unroll
        for (int ni = 0; ni < 4; ++ni)
          acc[mi][ni] = __builtin_amdgcn_mfma_f32_16x16x32_bf16(af[mi], bfr[ni], acc[mi][ni], 0, 0, 0);
    }
  }
#pragma unroll
  for (int mi = 0; mi < 4; ++mi)
#pragma unroll
    for (int ni = 0; ni < 4; ++ni)
#pragma unroll
      for (int r = 0; r < 4; ++r) {
        const int row = bm * 128 + wm + mi * 16 + lg * 4 + r;
        const int col = bn * 128 + wn + ni * 16 + ln;
        Cb[((size_t)z * M + row) * N + col] = __float2bfloat16(acc[mi][ni][r]);
      }
}

// ---------------- resid combine: out = resid + scale * sum(chunks) ---------
__global__ __launch_bounds__(256) void resid_combine(
    const bf16* __restrict__ Opc, int nc,
    const float* __restrict__ resid, const float* __restrict__ scale,
    float* __restrict__ outp)
{
  const int row = blockIdx.x * 4 + (threadIdx.x >> 6);
  const int lane = threadIdx.x & 63;
  f32x4 a0 = {}, a1 = {};
  for (int c = 0; c < nc; ++c) {
    const short8 u = *(const short8*)(Opc + ((size_t)c * T_DIM + row) * 512 + lane * 8);
#pragma unroll
    for (int j = 0; j < 4; ++j) {
      a0[j] += bfbits2f(u[j]);
      a1[j] += bfbits2f(u[j + 4]);
    }
  }
  const float* rp = resid + (size_t)row * 512 + lane * 8;
  const f32x4 r0 = *(const f32x4*)rp;
  const f32x4 r1 = *(const f32x4*)(rp + 4);
  const f32x4 s0 = *(const f32x4*)(scale + lane * 8);
  const f32x4 s1 = *(const f32x4*)(scale + lane * 8 + 4);
  f32x4 o0, o1;
#pragma unroll
  for (int j = 0; j < 4; ++j) {
    o0[j] = r0[j] + s0[j] * a0[j];
    o1[j] = r1[j] + s1[j] * a1[j];
  }
  float* op = outp + (size_t)row * 512 + lane * 8;
  *(f32x4*)op = o0;
  *(f32x4*)(op + 4) = o1;
}

// ---------------- GEMM C = A * B^T (256x128 tile, BK=64, 8 waves) ----------
// Used for qkv (N=1536, fused V transpose) and ffn1 (N=2048, gelu).
template <int MODE>
__global__ __launch_bounds__(512, 4) void gemm_bt256(
    const bf16* __restrict__ A, const bf16* __restrict__ B,
    int M, int N, int K,
    bf16* __restrict__ Cb, bf16* __restrict__ vTout)
{
  __shared__ bf16 sA[256 * 64];
  __shared__ bf16 sB[128 * 64];
  const int tid = threadIdx.x;
  const int lane = tid & 63, wave = tid >> 6;
  const int NB = gridDim.y;
  const int nwg = gridDim.x * NB;
  const int lin = blockIdx.y * gridDim.x + blockIdx.x;
  const int q8 = nwg >> 3;
  const int swz = (lin & 7) * q8 + (lin >> 3);
  const int bm = swz / NB, bn = swz % NB;
  const int wm = (wave & 3) * 64, wn = (wave >> 2) * 64;
  const int ln = lane & 15, lg = lane >> 4;
  f32x4 acc[4][4] = {};

  const int nkt = K >> 6;
  for (int kt = 0; kt < nkt; ++kt) {
    __syncthreads();
#pragma unroll
    for (int r = 0; r < 4; ++r) {
      const int s = r * 512 + tid;
      const int ks = s >> 10, rb = (s >> 6) & 15, l = s & 63;
      const bf16* srcA = A + (size_t)(bm * 256 + rb * 16 + (l & 15)) * K + kt * 64 + ks * 32 + (l >> 4) * 8;
      GLL16(srcA, sA + (size_t)(r * 512 + wave * 64) * 8);
    }
#pragma unroll
    for (int r = 0; r < 2; ++r) {
      const int s = r * 512 + tid;
      const int ks = s >> 9, rb = (s >> 6) & 7, l = s & 63;
      const bf16* srcB = B + (size_t)(bn * 128 + rb * 16 + (l & 15)) * K + kt * 64 + ks * 32 + (l >> 4) * 8;
      GLL16(srcB, sB + (size_t)(r * 512 + wave * 64) * 8);
    }
    __syncthreads();
#pragma unroll
    for (int ks = 0; ks < 2; ++ks) {
      short8 af[4], bfr[4];
#pragma unroll
      for (int mi = 0; mi < 4; ++mi)
        af[mi] = *(const short8*)(sA + (size_t)(ks * 1024 + ((wm >> 4) + mi) * 64 + lane) * 8);
#pragma unroll
      for (int ni = 0; ni < 4; ++ni)
        bfr[ni] = *(const short8*)(sB + (size_t)(ks * 512 + ((wn >> 4) + ni) * 64 + lane) * 8);
#pragma unroll
      for (int mi = 0; mi < 4; ++mi)
#pragma unroll
        for (int ni = 0; ni < 4; ++ni)
          acc[mi][ni] = __builtin_amdgcn_mfma_f32_16x16x32_bf16(af[mi], bfr[ni], acc[mi][ni], 0, 0, 0);
    }
  }
#pragma unroll
  for (int mi = 0; mi < 4; ++mi) {
#pragma unroll
    for (int ni = 0; ni < 4; ++ni) {
#pragma unroll
      for (int r = 0; r < 4; ++r) {
        const int row = bm * 256 + wm + mi * 16 + lg * 4 + r;
        const int col = bn * 128 + wn + ni * 16 + ln;
        const size_t idx = (size_t)row * N + col;
        float v = acc[mi][ni][r];
        if constexpr (MODE == MODE_GELU) { Cb[idx] = __float2bfloat16(gelu_f(v)); }
        else {
          const bf16 bv = __float2bfloat16(v);
          Cb[idx] = bv;
          if (vTout && bn >= 8)
            vTout[(size_t)(col - 1024) * T_DIM + row] = bv;
        }
      }
    }
  }
}

// ---------------- causal flash attention (8 waves, 128 rows, T4 + T13) ------
// (verified at 147us -- structural plateau)
__global__ __launch_bounds__(512, 2) void attn_kernel(
    const bf16* __restrict__ proj, const bf16* __restrict__ vT,
    bf16* __restrict__ Op, float* __restrict__ mlp)
{
  __shared__ bf16 sQ[2][32 * 512];
  __shared__ bf16 sV[2][32 * 512];
  __shared__ bf16 sP[8][16 * 40];

  const int tid = threadIdx.x, lane = tid & 63, wave = tid >> 6;
  const int ln = lane & 15, lg = lane >> 4;
  const int b = 511 - blockIdx.x;
  const int it = b >> 3;
  const int ch = b & 7;
  const int nj = 4 * it + 4;
  const int jlo = ch * nj / 8;
  const int jhi = (ch + 1) * nj / 8;
  const int wrow = it * 128 + wave * 16;

  short8 kf[16];
#pragma unroll
  for (int ks = 0; ks < 16; ++ks)
    kf[ks] = *(const short8*)(proj + (size_t)(wrow + ln) * 1536 + 512 + ks * 32 + lg * 8);

  f32x4 oa[32] = {};
  float m_r[4] = {-__builtin_inff(), -__builtin_inff(), -__builtin_inff(), -__builtin_inff()};
  float l_r[4] = {0.f, 0.f, 0.f, 0.f};

  auto stageQ = [&](int c, int jt) {
    const int j0 = jt * 32;
#pragma unroll
    for (int r = 0; r < 4; ++r) {
      const int s = r * 512 + tid;
      const int l = s & 63;
      const int ks = s >> 7, jb = (s >> 6) & 1;
      const bf16* srcQ = proj + (size_t)(j0 + jb * 16 + (l & 15)) * 1536 + ks * 32 + (l >> 4) * 8;
      GLL16(srcQ, &sQ[c][(size_t)(r * 512 + wave * 64) * 8]);
    }
  };
  auto stageV = [&](int c, int jt) {
    const int j0 = jt * 32;
#pragma unroll
    for (int r = 0; r < 4; ++r) {
      const int s = r * 512 + tid;
      const int l = s & 63;
      const int nb = s >> 6;
      const bf16* srcV = vT + (size_t)(nb * 16 + (l & 15)) * T_DIM + j0 + (l >> 4) * 8;
      GLL16(srcV, &sV[c][(size_t)(r * 512 + wave * 64) * 8]);
    }
  };

  if (jlo < jhi) {
    int cur = 0;
    stageQ(0, jlo);
    stageV(0, jlo);
    for (int jt = jlo; jt < jhi; ++jt) {
      const int j0 = jt * 32;
      const bool more = (jt + 1 < jhi);
      if (more) stageQ(cur ^ 1, jt + 1);
      if (more) { asm volatile("s_waitcnt vmcnt(8)" ::: "memory"); }
      else      { asm volatile("s_waitcnt vmcnt(4)" ::: "memory"); }
      __builtin_amdgcn_s_barrier();
      __builtin_amdgcn_sched_barrier(0);
      if (j0 <= wrow + 15) {
        f32x4 sfr[2] = {};
        __builtin_amdgcn_s_setprio(1);
#pragma unroll
        for (int ks = 0; ks < 16; ++ks) {
          short8 q0 = *(const short8*)(&sQ[cur][(size_t)(ks * 128 + lane) * 8]);
          short8 q1 = *(const short8*)(&sQ[cur][(size_t)(ks * 128 + 64 + lane) * 8]);
          sfr[0] = __builtin_amdgcn_mfma_f32_16x16x32_bf16(kf[ks], q0, sfr[0], 0, 0, 0);
          sfr[1] = __builtin_amdgcn_mfma_f32_16x16x32_bf16(kf[ks], q1, sfr[1], 0, 0, 0);
        }
        __builtin_amdgcn_s_setprio(0);
        if (j0 + 31 > wrow) {
#pragma unroll
          for (int jb = 0; jb < 2; ++jb)
#pragma unroll
            for (int r = 0; r < 4; ++r) {
              const int i = wrow + lg * 4 + r, j = j0 + jb * 16 + ln;
              if (j > i) sfr[jb][r] = -__builtin_inff();
            }
        }
        float mx[4];
#pragma unroll
        for (int r = 0; r < 4; ++r) mx[r] = fmaxf(sfr[0][r], sfr[1][r]);
#pragma unroll
        for (int d = 1; d < 16; d <<= 1)
#pragma unroll
          for (int r = 0; r < 4; ++r) mx[r] = fmaxf(mx[r], __shfl_xor(mx[r], d));
        bool need = false;
#pragma unroll
        for (int r = 0; r < 4; ++r) need |= !(mx[r] - m_r[r] <= 8.0f);
        if (__any(need)) {
          float sc[4];
#pragma unroll
          for (int r = 0; r < 4; ++r) {
            float mm = fmaxf(fmaxf(m_r[r], mx[r]), -1e30f);
            sc[r] = __expf(m_r[r] - mm);
            m_r[r] = mm;
            l_r[r] *= sc[r];
          }
#pragma unroll
          for (int nb = 0; nb < 32; ++nb)
#pragma unroll
            for (int r = 0; r < 4; ++r) oa[nb][r] *= sc[r];
        }
        float ts[4] = {0.f, 0.f, 0.f, 0.f};
#pragma unroll
        for (int jb = 0; jb < 2; ++jb)
#pragma unroll
          for (int r = 0; r < 4; ++r) {
            float p = __expf(sfr[jb][r] - m_r[r]);
            sfr[jb][r] = p;
            ts[r] += p;
          }
#pragma unroll
        for (int d = 1; d < 16; d <<= 1)
#pragma unroll
          for (int r = 0; r < 4; ++r) ts[r] += __shfl_xor(ts[r], d);
#pragma unroll
        for (int r = 0; r < 4; ++r) l_r[r] += ts[r];
#pragma unroll
        for (int jb = 0; jb < 2; ++jb)
#pragma unroll
          for (int r = 0; r < 4; ++r)
            sP[wave][(lg * 4 + r) * 40 + jb * 16 + ln] = __float2bfloat16(sfr[jb][r]);
      }
      if (more) stageV(cur ^ 1, jt + 1);
      if (more) { asm volatile("s_waitcnt vmcnt(8)" ::: "memory"); }
      else      { asm volatile("s_waitcnt vmcnt(0)" ::: "memory"); }
      __builtin_amdgcn_s_barrier();
      __builtin_amdgcn_sched_barrier(0);
      if (j0 <= wrow + 15) {
        const short8 pa = *(const short8*)(&sP[wave][0] + ln * 40 + lg * 8);
        __builtin_amdgcn_s_setprio(1);
#define LDV(nb) (*(const short8*)(&sV[cur][(size_t)((nb) * 64 + lane) * 8]))
        short8 vf0 = LDV(0), vf1 = LDV(1), vf2 = LDV(2), vf3 = LDV(3);
#pragma unroll
        for (int nb = 0; nb < 28; nb += 4) {
          const short8 w0 = vf0, w1 = vf1, w2 = vf2, w3 = vf3;
          vf0 = LDV(nb + 4); vf1 = LDV(nb + 5); vf2 = LDV(nb + 6); vf3 = LDV(nb + 7);
          oa[nb]     = __builtin_amdgcn_mfma_f32_16x16x32_bf16(pa, w0, oa[nb],     0, 0, 0);
          oa[nb + 1] = __builtin_amdgcn_mfma_f32_16x16x32_bf16(pa, w1, oa[nb + 1], 0, 0, 0);
          oa[nb + 2] = __builtin_amdgcn_mfma_f32_16x16x32_bf16(pa, w2, oa[nb + 2], 0, 0, 0);
          oa[nb + 3] = __builtin_amdgcn_mfma_f32_16x16x32_bf16(pa, w3, oa[nb + 3], 0, 0, 0);
        }
        oa[28] = __builtin_amdgcn_mfma_f32_16x16x32_bf16(pa, vf0, oa[28], 0, 0, 0);
        oa[29] = __builtin_amdgcn_mfma_f32_16x16x32_bf16(pa, vf1, oa[29], 0, 0, 0);
        oa[30] = __builtin_amdgcn_mfma_f32_16x16x32_bf16(pa, vf2, oa[30], 0, 0, 0);
        oa[31] = __builtin_amdgcn_mfma_f32_16x16x32_bf16(pa, vf3, oa[31], 0, 0, 0);
#undef LDV
        __builtin_amdgcn_s_setprio(0);
      }
      cur ^= 1;
    }
  }
#pragma unroll
  for (int nb = 0; nb < 32; ++nb)
#pragma unroll
    for (int r = 0; r < 4; ++r)
      Op[((size_t)ch * T_DIM + wrow + lg * 4 + r) * 512 + nb * 16 + ln] = __float2bfloat16(oa[nb][r]);
  if (ln == 0) {
#pragma unroll
    for (int r = 0; r < 4; ++r) {
      mlp[((size_t)ch * T_DIM + wrow + lg * 4 + r) * 2 + 0] = m_r[r];
      mlp[((size_t)ch * T_DIM + wrow + lg * 4 + r) * 2 + 1] = l_r[r];
    }
  }
}

// ---------------- merge attention partials -> o bf16 [T,512] ----------------
__global__ __launch_bounds__(256) void combine_kernel(
    const bf16* __restrict__ Op, const float* __restrict__ mlp, bf16* __restrict__ o)
{
  const int row = blockIdx.x * 4 + (threadIdx.x >> 6);
  const int lane = threadIdx.x & 63;
  const int k = 8;
  float m = -__builtin_inff();
  for (int c = 0; c < k; ++c) m = fmaxf(m, mlp[((size_t)c * T_DIM + row) * 2]);
  float l = 0.f;
  for (int c = 0; c < k; ++c) {
    const float mc = mlp[((size_t)c * T_DIM + row) * 2];
    const float lc = mlp[((size_t)c * T_DIM + row) * 2 + 1];
    l += __expf(mc - m) * lc;
  }
  const float inv = 1.0f / l;
  f32x4 a0 = {}, a1 = {};
  for (int c = 0; c < k; ++c) {
    const float w = __expf(mlp[((size_t)c * T_DIM + row) * 2] - m);
    const short8 u = *(const short8*)(Op + ((size_t)c * T_DIM + row) * 512 + lane * 8);
#pragma unroll
    for (int j = 0; j < 4; ++j) {
      a0[j] += w * bfbits2f(u[j]);
      a1[j] += w * bfbits2f(u[j + 4]);
    }
  }
  short8 ov;
#pragma unroll
  for (int j = 0; j < 4; ++j) {
    ov[j]     = f2bfbits(a0[j] * inv);
    ov[j + 4] = f2bfbits(a1[j] * inv);
  }
  *(short8*)(o + (size_t)row * 512 + lane * 8) = ov;
}

// ---------------- launch ----------------
extern "C" void kernel_launch(void* const* d_in, const int* in_sizes, int n_in,
                              void* d_out, int out_size, void* d_ws, size_t ws_size,
                              hipStream_t stream) {
  (void)in_sizes; (void)n_in; (void)out_size; (void)ws_size;
  const float* x    = (const float*)d_in[0];
  const float* Win  = (const float*)d_in[1];
  const float* Wout = (const float*)d_in[2];
  const float* W1   = (const float*)d_in[3];
  const float* W2   = (const float*)d_in[4];
  const float* g1   = (const float*)d_in[5];
  const float* b1   = (const float*)d_in[6];
  const float* g2   = (const float*)d_in[7];
  const float* b2   = (const float*)d_in[8];
  const float* ls1  = (const float*)d_in[9];
  const float* ls2  = (const float*)d_in[10];
  float* out = (float*)d_out;

  char* w = (char*)d_ws;
  size_t off = 0;
  auto alloc = [&](size_t bytes) -> char* {
    char* p = w + off; off += (bytes + 255) & ~(size_t)255; return p;
  };
  bf16* wWin  = (bf16*)alloc((size_t)1536 * 512 * 2);
  bf16* wWout = (bf16*)alloc((size_t)512 * 512 * 2);
  bf16* wW1   = (bf16*)alloc((size_t)2048 * 512 * 2);
  bf16* wW2   = (bf16*)alloc((size_t)512 * 2048 * 2);
  bf16* h     = (bf16*)alloc((size_t)T_DIM * 512 * 2);    // LN1 out; reused for LN2 out
  bf16* proj  = (bf16*)alloc((size_t)T_DIM * 1536 * 2);   // q|k|v
  bf16* vTb   = (bf16*)alloc((size_t)512 * T_DIM * 2);
  bf16* o     = (bf16*)alloc((size_t)T_DIM * 512 * 2);
  float* x1   = (float*)alloc((size_t)T_DIM * 512 * 4);
  bf16* Op    = (bf16*)alloc((size_t)8 * T_DIM * 512 * 2); // 67MB bf16 partials
  float* mlp  = (float*)alloc((size_t)8 * T_DIM * 2 * 4);
  bf16* f1  = proj;   // ffn1 out aliases proj||vT (dead after attention)
  bf16* Opf = Op;     // ffn2 split-K partials (2 slices) alias Op (dead after combine)

  cvt4_kernel<<<(1536 * 512 + 512 * 512 + 2048 * 512 + 512 * 2048) / 4 / 256, 256, 0, stream>>>(
      Win, wWin, 1536 * 512, Wout, wWout, 512 * 512,
      W1, wW1, 2048 * 512, W2, wW2, 512 * 2048);

  ln_kernel<<<T_DIM / 4, 256, 0, stream>>>(x, g1, b1, h);
  gemm_bt256<MODE_BF16><<<dim3(32, 12), 512, 0, stream>>>(h, wWin, 8192, 1536, 512, proj, vTb);
  attn_kernel<<<512, 512, 0, stream>>>(proj, vTb, Op, mlp);
  combine_kernel<<<T_DIM / 4, 256, 0, stream>>>(Op, mlp, o);
  gemm_bt<MODE_RESID><<<dim3(64, 4), 256, 0, stream>>>(o, wWout, 8192, 512, 512, nullptr, x1, x, ls1, nullptr);
  ln_kernel<<<T_DIM / 4, 256, 0, stream>>>(x1, g2, b2, h);
  gemm_bt256<MODE_GELU><<<dim3(32, 16), 512, 0, stream>>>(h, wW1, 8192, 2048, 512, f1, nullptr);
  // ffn2: split-K x2 (Kc=1024, ld=2048) -> 512 blocks (2 blocks/CU), then
  // out = x1 + ls2 * (chunk0 + chunk1).
  gemm_bt_splitk<<<dim3(64, 4, 2), 256, 0, stream>>>(f1, wW2, 8192, 512, 1024, 2048, Opf);
  resid_combine<<<T_DIM / 4, 256, 0, stream>>>(Opf, 2, x1, ls2, out);
}